// Round 12
// baseline (1287.484 us; speedup 1.0000x reference)
//
#include <hip/hip_runtime.h>

// Persistent fused 2-layer LSTM + FC + softmax for MI355X (gfx950).
// B=2048, T=256, H=64, IN=42. R19: 512 blocks x 512 threads; block owns
// 4 rows -> TWO independent blocks per CU. Waves 0-3 (A): layer0(step i);
// waves 4-7 (B): layer1(step i-1) — unchanged R15 schedule.
//
// Rationale: R15 (174us) is issue/convoy-bound at 1 block/CU — all 8
// waves of a CU meet one barrier; SIMDs idle during the convoy. Three
// isolated schedule perturbations (R16 setprio, R17 stride, R18
// pre-barrier MFMA) all regressed -> the step body is compiler-optimal.
// R19 changes ONLY the TLP structure: halve rows/block, double blocks.
// Each SIMD now hosts waves from 2 independent barriers; when one block
// convoys, the other issues. MFMA issue doubles (slack), activation per
// wave halves (1 cell/lane), VGPR 96 <= 128 for 4 waves/SIMD.
//
// Row map at kRows=4: batch row r lives at tile row 4r (rows {0,4,8,12});
// lane (c,quad) owns the cell at D row quad*4 = batch row quad (acc elem 0).
// Pad tile rows stay zero / garbage and land in discarded D rows.
//
// Carried from R14/R15:
//  - x feeds layer0 MFMA chunks 2,3 from per-lane global loads (tile row
//    c sources batch row c>>2); k>=106 zero weight cols mask the tail;
//    kOfsMax clamp keeps loads in-bounds.
//  - common-denominator activations: 7 trans/cell (5 exp2 + 2 rcp).
//  - bias as MFMA C operand; weights pre-scaled by log2e / 2*log2e.
//  - lgkmcnt-only barrier in the hot loop; kP=72 (16B-aligned rows).

typedef _Float16 f16;
typedef _Float16 f16x2 __attribute__((ext_vector_type(2)));
typedef _Float16 f16x8 __attribute__((ext_vector_type(8)));
typedef float f32x4 __attribute__((ext_vector_type(4)));

namespace {
constexpr int kT = 256;
constexpr int kIn = 42;
constexpr int kH = 64;
constexpr int kRows = 4;          // real batch rows per block (R19: was 8)
constexpr int kThr = 512;
constexpr int kBlocks = 512;      // 2048/4 -> 2 blocks per CU
constexpr int kP = 72;            // LDS row stride f16 (144 B, 16B-aligned)
constexpr int kS = 16 * kP;       // one ping-pong slot (16 tile rows)
constexpr float kL2E = 1.44269504088896f;   // log2(e)
constexpr float kM2L = -2.0f * kL2E;
constexpr unsigned kNTot = 2048u * 256u * 42u;   // total floats in x
constexpr unsigned kOfsMax = kNTot - 64u;        // clamp so +63 floats stays in-bounds
}

__device__ __forceinline__ float ex2_(float v) { return __builtin_amdgcn_exp2f(v); }
__device__ __forceinline__ float rcp_(float v) { return __builtin_amdgcn_rcpf(v); }
__device__ __forceinline__ f16x2 pk_(float a, float b) {
  return __builtin_bit_cast(f16x2, __builtin_amdgcn_cvt_pkrtz(a, b));
}
// Barrier that publishes LDS writes but does NOT drain vmem (private x
// prefetch stays in flight).
__device__ __forceinline__ void bar_lds_() {
  asm volatile("s_waitcnt lgkmcnt(0)" ::: "memory");
  __builtin_amdgcn_s_barrier();
}

__global__ __launch_bounds__(kThr, 4)
void lstm_r19_kernel(const float* __restrict__ x,
                     const float* __restrict__ Wih0, const float* __restrict__ Whh0,
                     const float* __restrict__ bih0, const float* __restrict__ bhh0,
                     const float* __restrict__ Wih1, const float* __restrict__ Whh1,
                     const float* __restrict__ bih1, const float* __restrict__ bhh1,
                     const float* __restrict__ Wfc, const float* __restrict__ bfc,
                     float* __restrict__ out) {
  __shared__ __align__(16) f16 xh0[2 * kS];
  __shared__ __align__(16) f16 xh1[2 * kS];
  __shared__ float lg[kRows * 8];

  const int tid = threadIdx.x;
  const int w8 = tid >> 6;
  const bool isA = (w8 < 4);     // A: layer 0; B: layer 1
  const int w = w8 & 3;          // gate-col slice [16w, 16w+16)
  const int l = tid & 63;
  const int c = l & 15;
  const int quad = l >> 4;
  const int row0 = blockIdx.x * kRows;

  for (int i = tid; i < 2 * kS; i += kThr) { xh0[i] = (f16)0; xh1[i] = (f16)0; }

  // ---- one-time: weights as MFMA B-fragments (pre-scaled) + bias4 ----
  f16x8 Bw[4][4];
  f32x4 bias4[4];
#pragma unroll
  for (int a = 0; a < 4; ++a) {
    const int g = (w + 4 * a) * 16 + c;
    const float scale = (a == 2) ? 2.0f * kL2E : kL2E;  // g-gate gets 2*log2e
    const float b = (isA ? (bih0[g] + bhh0[g]) : (bih1[g] + bhh1[g])) * scale;
    bias4[a] = (f32x4){b, b, b, b};
#pragma unroll
    for (int q = 0; q < 4; ++q) {
      f16x8 v;
#pragma unroll
      for (int j = 0; j < 8; ++j) {
        const int k = q * 32 + quad * 8 + j;
        float wv;
        if (isA)  // layer0 A = [h0 (k<64) | x (64<=k<106) | 0]
          wv = (k < 64) ? Whh0[g * kH + k] : (k < 106) ? Wih0[g * kIn + (k - 64)] : 0.f;
        else      // layer1 A = [h0 (k<64) | h1]
          wv = (k < 64) ? Wih1[g * kH + k] : Whh1[g * kH + (k - 64)];
        v[j] = (f16)(wv * scale);
      }
      Bw[a][q] = v;
    }
  }

  // ---- LDS pointers (lane reads tile row c) ----
  const f16* rbh[2];   // h0 chunks 0,1 (A and B)
  rbh[0] = xh0 + c * kP + quad * 8;
  rbh[1] = rbh[0] + kS;
  const f16* rb1[2];   // h1 chunks (B only)
  rb1[0] = xh1 + c * kP + quad * 8;
  rb1[1] = rb1[0] + kS;

  // h write: lane's cell is batch row quad at tile row quad*4, col hcol.
  const int hcol = w * 16 + c;
  f16* wp[2];
  {
    f16* base = isA ? xh0 : xh1;
    wp[0] = base + (quad * 4) * kP + hcol;
    wp[1] = wp[0] + kS;
  }

  float cst = 0.f;   // single cell per lane (batch row quad)

  // ---- A-wave register x pipeline (prefetch depth 2) ----
  // Tile row c sources batch row c>>2 (real when c%4==0; alias otherwise).
  const int xr = c >> 2;
  const unsigned fc2 = (unsigned)(quad * 8);
  const unsigned fc3 = 32u + (unsigned)(quad * 8);
  unsigned ofs = (unsigned)(row0 + xr) * (unsigned)(kT * kIn);

  float2 rawA[8], rawB[8];
  f16x8 fx2{}, fx3{};

  auto issueX = [&](float2 (&r)[8], unsigned o) {
    const float* p = x + (o < kOfsMax ? o : kOfsMax);
#pragma unroll
    for (int j = 0; j < 4; ++j) {
      r[j]     = *(const float2*)(p + fc2 + 2 * j);
      r[4 + j] = *(const float2*)(p + fc3 + 2 * j);
    }
  };
  auto cvtX = [&](const float2 (&r)[8]) {
    struct H4 { f16x2 a, b, c, d; };
    H4 h2, h3;
    h2.a = pk_(r[0].x, r[0].y);
    h2.b = pk_(r[1].x, r[1].y);
    h2.c = pk_(r[2].x, r[2].y);
    h2.d = pk_(r[3].x, r[3].y);
    h3.a = pk_(r[4].x, r[4].y);
    h3.b = pk_(r[5].x, r[5].y);
    h3.c = pk_(r[6].x, r[6].y);
    h3.d = pk_(r[7].x, r[7].y);
    fx2 = __builtin_bit_cast(f16x8, h2);
    fx3 = __builtin_bit_cast(f16x8, h3);
  };

  if (isA) {
    issueX(rawB, ofs);            // x(0)
    cvtX(rawB);                   // fx = x(0)
    issueX(rawA, ofs + kIn);      // x(1) in flight
    ofs += 2u * kIn;              // next issue: t = 2
  }
  __syncthreads();  // startup barrier (full drain once is fine)

  // iter i: A computes layer0(t=i) (i<kT), B computes layer1(t=i-1) (i>0).
  auto step = [&](int i, int par, bool even) {
    const int nxt = par ^ 1;
    const bool act = isA ? (i < kT) : (i > 0);

    if (act) {
      f32x4 acc[4];
      if (isA) {
        // x chunks first: register-resident, overlap the h0 ds_reads.
#pragma unroll
        for (int a = 0; a < 4; ++a)
          acc[a] = __builtin_amdgcn_mfma_f32_16x16x32_f16(fx2, Bw[a][2], bias4[a], 0, 0, 0);
#pragma unroll
        for (int a = 0; a < 4; ++a)
          acc[a] = __builtin_amdgcn_mfma_f32_16x16x32_f16(fx3, Bw[a][3], acc[a], 0, 0, 0);
        const f16x8 A0 = __builtin_bit_cast(f16x8, *(const float4*)(rbh[par]));
        const f16x8 A1 = __builtin_bit_cast(f16x8, *(const float4*)(rbh[par] + 32));
#pragma unroll
        for (int a = 0; a < 4; ++a)
          acc[a] = __builtin_amdgcn_mfma_f32_16x16x32_f16(A0, Bw[a][0], acc[a], 0, 0, 0);
#pragma unroll
        for (int a = 0; a < 4; ++a)
          acc[a] = __builtin_amdgcn_mfma_f32_16x16x32_f16(A1, Bw[a][1], acc[a], 0, 0, 0);
      } else {
        const f16x8 A0 = __builtin_bit_cast(f16x8, *(const float4*)(rbh[par]));
        const f16x8 A1 = __builtin_bit_cast(f16x8, *(const float4*)(rbh[par] + 32));
        const f16x8 A2 = __builtin_bit_cast(f16x8, *(const float4*)(rb1[par]));
        const f16x8 A3 = __builtin_bit_cast(f16x8, *(const float4*)(rb1[par] + 32));
#pragma unroll
        for (int a = 0; a < 4; ++a)
          acc[a] = __builtin_amdgcn_mfma_f32_16x16x32_f16(A0, Bw[a][0], bias4[a], 0, 0, 0);
#pragma unroll
        for (int a = 0; a < 4; ++a)
          acc[a] = __builtin_amdgcn_mfma_f32_16x16x32_f16(A1, Bw[a][1], acc[a], 0, 0, 0);
#pragma unroll
        for (int a = 0; a < 4; ++a)
          acc[a] = __builtin_amdgcn_mfma_f32_16x16x32_f16(A2, Bw[a][2], acc[a], 0, 0, 0);
#pragma unroll
        for (int a = 0; a < 4; ++a)
          acc[a] = __builtin_amdgcn_mfma_f32_16x16x32_f16(A3, Bw[a][3], acc[a], 0, 0, 0);
      }

      // common-denominator activation, single cell (acc elem 0):
      // 7 trans (5 exp2 + 2 rcp)
      {
        const float ei = ex2_(-acc[0][0]);
        const float ef = ex2_(-acc[1][0]);
        const float eg = ex2_(-acc[2][0]);
        const float eo = ex2_(-acc[3][0]);
        const float pi = 1.0f + ei, pf = 1.0f + ef, pg = 1.0f + eg, po = 1.0f + eo;
        const float mg = 1.0f - eg;
        const float t1 = pi * pg;
        const float t2 = mg * pf;
        const float N  = fmaf(cst, t1, t2);
        const float cn = N * rcp_(t1 * pf);
        cst = cn;
        const float ec = ex2_(cn * kM2L);
        const float h  = (1.0f - ec) * rcp_(po * (1.0f + ec));
        wp[nxt][0] = (f16)h;
      }
    }
    if (isA) {
      if (even) { issueX(rawB, ofs); cvtX(rawA); }   // issue x(i+2), cvt x(i+1)
      else      { issueX(rawA, ofs); cvtX(rawB); }
      ofs += (unsigned)kIn;
    }
    bar_lds_();  // publish h writes (lgkmcnt only); x loads stay in flight
  };

  for (int i = 0; i < kT; i += 2) { step(i, 0, true); step(i + 1, 1, false); }
  step(kT, 0, true);  // drain: B computes h1(T-1) -> xh1 slot 1

  // ---- FC + softmax. Final h1(T-1) is in xh1 slot 1 (tile row 4*rr). ----
  if (tid < kRows * 5) {
    const int rr = tid / 5, oo = tid - rr * 5;
    float a = bfc[oo];
#pragma unroll
    for (int j = 0; j < kH; ++j)
      a += (float)xh1[kS + (4 * rr) * kP + j] * Wfc[oo * kH + j];
    lg[rr * 8 + oo] = a;
  }
  __syncthreads();
  if (tid < kRows) {
    const float v0 = lg[tid * 8 + 0], v1 = lg[tid * 8 + 1], v2 = lg[tid * 8 + 2],
                v3 = lg[tid * 8 + 3], v4 = lg[tid * 8 + 4];
    const float m = fmaxf(fmaxf(fmaxf(v0, v1), fmaxf(v2, v3)), v4);
    const float e0 = __expf(v0 - m), e1 = __expf(v1 - m), e2 = __expf(v2 - m),
                e3 = __expf(v3 - m), e4 = __expf(v4 - m);
    const float inv = __fdividef(1.0f, e0 + e1 + e2 + e3 + e4);
    float* o = out + (size_t)(row0 + tid) * 5;
    o[0] = e0 * inv; o[1] = e1 * inv; o[2] = e2 * inv; o[3] = e3 * inv; o[4] = e4 * inv;
  }
}

extern "C" void kernel_launch(void* const* d_in, const int* in_sizes, int n_in,
                              void* d_out, int out_size, void* d_ws, size_t ws_size,
                              hipStream_t stream) {
  (void)in_sizes; (void)n_in; (void)d_ws; (void)ws_size; (void)out_size;
  lstm_r19_kernel<<<dim3(kBlocks), dim3(kThr), 0, stream>>>(
      (const float*)d_in[0],
      (const float*)d_in[1], (const float*)d_in[2],
      (const float*)d_in[3], (const float*)d_in[4],
      (const float*)d_in[5], (const float*)d_in[6],
      (const float*)d_in[7], (const float*)d_in[8],
      (const float*)d_in[9], (const float*)d_in[10],
      (float*)d_out);
}

// Round 13
// 450.613 us; speedup vs baseline: 2.8572x; 2.8572x over previous
//
#include <hip/hip_runtime.h>

// Persistent fused 2-layer LSTM + FC + softmax for MI355X (gfx950).
// B=2048, T=256, H=64, IN=42. R20: 512 blocks x 512 threads; block owns
// 4 rows -> TWO independent blocks per CU. Waves 0-3 (A): layer0(step i);
// waves 4-7 (B): layer1(step i-1) — unchanged R15 schedule.
//
// R20 = R19 with __launch_bounds__(512, 2). R19's (512,4) was interpreted
// as min-BLOCKS/CU (CUDA semantics on this ROCm): 4 blocks -> 8 waves/SIMD
// -> 64-VGPR budget -> Bw/raw arrays spilled to scratch (WRITE_SIZE 40KB ->
// 1.78GB, FETCH 44MB -> 787MB, 1224us). With (512,2): budget 128, compiler
// lands ~96 VGPR (as R15-R18); 2 blocks/CU fit in hardware (4 waves/SIMD x
// 96 = 384 <= 512 VGPRs; 2 x 9.7KB LDS). This is the clean test of the
// TLP theory: independent per-block barriers overlap the convoy.
//
// Row map at kRows=4: batch row r lives at tile row 4r; lane (c,quad) owns
// the cell at D row quad*4 = batch row quad (acc elem 0). Pad tile rows
// stay zero/garbage and land in discarded D rows.
//
// Carried from R14/R15:
//  - x feeds layer0 MFMA chunks 2,3 from per-lane global loads (tile row
//    c sources batch row c>>2); k>=106 zero weight cols mask the tail;
//    kOfsMax clamp keeps loads in-bounds.
//  - common-denominator activations: 7 trans/cell (5 exp2 + 2 rcp).
//  - bias as MFMA C operand; weights pre-scaled by log2e / 2*log2e.
//  - lgkmcnt-only barrier in the hot loop; kP=72 (16B-aligned rows).

typedef _Float16 f16;
typedef _Float16 f16x2 __attribute__((ext_vector_type(2)));
typedef _Float16 f16x8 __attribute__((ext_vector_type(8)));
typedef float f32x4 __attribute__((ext_vector_type(4)));

namespace {
constexpr int kT = 256;
constexpr int kIn = 42;
constexpr int kH = 64;
constexpr int kRows = 4;          // real batch rows per block
constexpr int kThr = 512;
constexpr int kBlocks = 512;      // 2048/4 -> 2 blocks per CU
constexpr int kP = 72;            // LDS row stride f16 (144 B, 16B-aligned)
constexpr int kS = 16 * kP;       // one ping-pong slot (16 tile rows)
constexpr float kL2E = 1.44269504088896f;   // log2(e)
constexpr float kM2L = -2.0f * kL2E;
constexpr unsigned kNTot = 2048u * 256u * 42u;   // total floats in x
constexpr unsigned kOfsMax = kNTot - 64u;        // clamp so +63 floats stays in-bounds
}

__device__ __forceinline__ float ex2_(float v) { return __builtin_amdgcn_exp2f(v); }
__device__ __forceinline__ float rcp_(float v) { return __builtin_amdgcn_rcpf(v); }
__device__ __forceinline__ f16x2 pk_(float a, float b) {
  return __builtin_bit_cast(f16x2, __builtin_amdgcn_cvt_pkrtz(a, b));
}
// Barrier that publishes LDS writes but does NOT drain vmem (private x
// prefetch stays in flight).
__device__ __forceinline__ void bar_lds_() {
  asm volatile("s_waitcnt lgkmcnt(0)" ::: "memory");
  __builtin_amdgcn_s_barrier();
}

__global__ __launch_bounds__(kThr, 2)
void lstm_r20_kernel(const float* __restrict__ x,
                     const float* __restrict__ Wih0, const float* __restrict__ Whh0,
                     const float* __restrict__ bih0, const float* __restrict__ bhh0,
                     const float* __restrict__ Wih1, const float* __restrict__ Whh1,
                     const float* __restrict__ bih1, const float* __restrict__ bhh1,
                     const float* __restrict__ Wfc, const float* __restrict__ bfc,
                     float* __restrict__ out) {
  __shared__ __align__(16) f16 xh0[2 * kS];
  __shared__ __align__(16) f16 xh1[2 * kS];
  __shared__ float lg[kRows * 8];

  const int tid = threadIdx.x;
  const int w8 = tid >> 6;
  const bool isA = (w8 < 4);     // A: layer 0; B: layer 1
  const int w = w8 & 3;          // gate-col slice [16w, 16w+16)
  const int l = tid & 63;
  const int c = l & 15;
  const int quad = l >> 4;
  const int row0 = blockIdx.x * kRows;

  for (int i = tid; i < 2 * kS; i += kThr) { xh0[i] = (f16)0; xh1[i] = (f16)0; }

  // ---- one-time: weights as MFMA B-fragments (pre-scaled) + bias4 ----
  f16x8 Bw[4][4];
  f32x4 bias4[4];
#pragma unroll
  for (int a = 0; a < 4; ++a) {
    const int g = (w + 4 * a) * 16 + c;
    const float scale = (a == 2) ? 2.0f * kL2E : kL2E;  // g-gate gets 2*log2e
    const float b = (isA ? (bih0[g] + bhh0[g]) : (bih1[g] + bhh1[g])) * scale;
    bias4[a] = (f32x4){b, b, b, b};
#pragma unroll
    for (int q = 0; q < 4; ++q) {
      f16x8 v;
#pragma unroll
      for (int j = 0; j < 8; ++j) {
        const int k = q * 32 + quad * 8 + j;
        float wv;
        if (isA)  // layer0 A = [h0 (k<64) | x (64<=k<106) | 0]
          wv = (k < 64) ? Whh0[g * kH + k] : (k < 106) ? Wih0[g * kIn + (k - 64)] : 0.f;
        else      // layer1 A = [h0 (k<64) | h1]
          wv = (k < 64) ? Wih1[g * kH + k] : Whh1[g * kH + (k - 64)];
        v[j] = (f16)(wv * scale);
      }
      Bw[a][q] = v;
    }
  }

  // ---- LDS pointers (lane reads tile row c) ----
  const f16* rbh[2];   // h0 chunks 0,1 (A and B)
  rbh[0] = xh0 + c * kP + quad * 8;
  rbh[1] = rbh[0] + kS;
  const f16* rb1[2];   // h1 chunks (B only)
  rb1[0] = xh1 + c * kP + quad * 8;
  rb1[1] = rb1[0] + kS;

  // h write: lane's cell is batch row quad at tile row quad*4, col hcol.
  const int hcol = w * 16 + c;
  f16* wp[2];
  {
    f16* base = isA ? xh0 : xh1;
    wp[0] = base + (quad * 4) * kP + hcol;
    wp[1] = wp[0] + kS;
  }

  float cst = 0.f;   // single cell per lane (batch row quad)

  // ---- A-wave register x pipeline (prefetch depth 2) ----
  // Tile row c sources batch row c>>2 (real when c%4==0; alias otherwise).
  const int xr = c >> 2;
  const unsigned fc2 = (unsigned)(quad * 8);
  const unsigned fc3 = 32u + (unsigned)(quad * 8);
  unsigned ofs = (unsigned)(row0 + xr) * (unsigned)(kT * kIn);

  float2 rawA[8], rawB[8];
  f16x8 fx2{}, fx3{};

  auto issueX = [&](float2 (&r)[8], unsigned o) {
    const float* p = x + (o < kOfsMax ? o : kOfsMax);
#pragma unroll
    for (int j = 0; j < 4; ++j) {
      r[j]     = *(const float2*)(p + fc2 + 2 * j);
      r[4 + j] = *(const float2*)(p + fc3 + 2 * j);
    }
  };
  auto cvtX = [&](const float2 (&r)[8]) {
    struct H4 { f16x2 a, b, c, d; };
    H4 h2, h3;
    h2.a = pk_(r[0].x, r[0].y);
    h2.b = pk_(r[1].x, r[1].y);
    h2.c = pk_(r[2].x, r[2].y);
    h2.d = pk_(r[3].x, r[3].y);
    h3.a = pk_(r[4].x, r[4].y);
    h3.b = pk_(r[5].x, r[5].y);
    h3.c = pk_(r[6].x, r[6].y);
    h3.d = pk_(r[7].x, r[7].y);
    fx2 = __builtin_bit_cast(f16x8, h2);
    fx3 = __builtin_bit_cast(f16x8, h3);
  };

  if (isA) {
    issueX(rawB, ofs);            // x(0)
    cvtX(rawB);                   // fx = x(0)
    issueX(rawA, ofs + kIn);      // x(1) in flight
    ofs += 2u * kIn;              // next issue: t = 2
  }
  __syncthreads();  // startup barrier (full drain once is fine)

  // iter i: A computes layer0(t=i) (i<kT), B computes layer1(t=i-1) (i>0).
  auto step = [&](int i, int par, bool even) {
    const int nxt = par ^ 1;
    const bool act = isA ? (i < kT) : (i > 0);

    if (act) {
      f32x4 acc[4];
      if (isA) {
        // x chunks first: register-resident, overlap the h0 ds_reads.
#pragma unroll
        for (int a = 0; a < 4; ++a)
          acc[a] = __builtin_amdgcn_mfma_f32_16x16x32_f16(fx2, Bw[a][2], bias4[a], 0, 0, 0);
#pragma unroll
        for (int a = 0; a < 4; ++a)
          acc[a] = __builtin_amdgcn_mfma_f32_16x16x32_f16(fx3, Bw[a][3], acc[a], 0, 0, 0);
        const f16x8 A0 = __builtin_bit_cast(f16x8, *(const float4*)(rbh[par]));
        const f16x8 A1 = __builtin_bit_cast(f16x8, *(const float4*)(rbh[par] + 32));
#pragma unroll
        for (int a = 0; a < 4; ++a)
          acc[a] = __builtin_amdgcn_mfma_f32_16x16x32_f16(A0, Bw[a][0], acc[a], 0, 0, 0);
#pragma unroll
        for (int a = 0; a < 4; ++a)
          acc[a] = __builtin_amdgcn_mfma_f32_16x16x32_f16(A1, Bw[a][1], acc[a], 0, 0, 0);
      } else {
        const f16x8 A0 = __builtin_bit_cast(f16x8, *(const float4*)(rbh[par]));
        const f16x8 A1 = __builtin_bit_cast(f16x8, *(const float4*)(rbh[par] + 32));
        const f16x8 A2 = __builtin_bit_cast(f16x8, *(const float4*)(rb1[par]));
        const f16x8 A3 = __builtin_bit_cast(f16x8, *(const float4*)(rb1[par] + 32));
#pragma unroll
        for (int a = 0; a < 4; ++a)
          acc[a] = __builtin_amdgcn_mfma_f32_16x16x32_f16(A0, Bw[a][0], bias4[a], 0, 0, 0);
#pragma unroll
        for (int a = 0; a < 4; ++a)
          acc[a] = __builtin_amdgcn_mfma_f32_16x16x32_f16(A1, Bw[a][1], acc[a], 0, 0, 0);
#pragma unroll
        for (int a = 0; a < 4; ++a)
          acc[a] = __builtin_amdgcn_mfma_f32_16x16x32_f16(A2, Bw[a][2], acc[a], 0, 0, 0);
#pragma unroll
        for (int a = 0; a < 4; ++a)
          acc[a] = __builtin_amdgcn_mfma_f32_16x16x32_f16(A3, Bw[a][3], acc[a], 0, 0, 0);
      }

      // common-denominator activation, single cell (acc elem 0):
      // 7 trans (5 exp2 + 2 rcp)
      {
        const float ei = ex2_(-acc[0][0]);
        const float ef = ex2_(-acc[1][0]);
        const float eg = ex2_(-acc[2][0]);
        const float eo = ex2_(-acc[3][0]);
        const float pi = 1.0f + ei, pf = 1.0f + ef, pg = 1.0f + eg, po = 1.0f + eo;
        const float mg = 1.0f - eg;
        const float t1 = pi * pg;
        const float t2 = mg * pf;
        const float N  = fmaf(cst, t1, t2);
        const float cn = N * rcp_(t1 * pf);
        cst = cn;
        const float ec = ex2_(cn * kM2L);
        const float h  = (1.0f - ec) * rcp_(po * (1.0f + ec));
        wp[nxt][0] = (f16)h;
      }
    }
    if (isA) {
      if (even) { issueX(rawB, ofs); cvtX(rawA); }   // issue x(i+2), cvt x(i+1)
      else      { issueX(rawA, ofs); cvtX(rawB); }
      ofs += (unsigned)kIn;
    }
    bar_lds_();  // publish h writes (lgkmcnt only); x loads stay in flight
  };

  for (int i = 0; i < kT; i += 2) { step(i, 0, true); step(i + 1, 1, false); }
  step(kT, 0, true);  // drain: B computes h1(T-1) -> xh1 slot 1

  // ---- FC + softmax. Final h1(T-1) is in xh1 slot 1 (tile row 4*rr). ----
  if (tid < kRows * 5) {
    const int rr = tid / 5, oo = tid - rr * 5;
    float a = bfc[oo];
#pragma unroll
    for (int j = 0; j < kH; ++j)
      a += (float)xh1[kS + (4 * rr) * kP + j] * Wfc[oo * kH + j];
    lg[rr * 8 + oo] = a;
  }
  __syncthreads();
  if (tid < kRows) {
    const float v0 = lg[tid * 8 + 0], v1 = lg[tid * 8 + 1], v2 = lg[tid * 8 + 2],
                v3 = lg[tid * 8 + 3], v4 = lg[tid * 8 + 4];
    const float m = fmaxf(fmaxf(fmaxf(v0, v1), fmaxf(v2, v3)), v4);
    const float e0 = __expf(v0 - m), e1 = __expf(v1 - m), e2 = __expf(v2 - m),
                e3 = __expf(v3 - m), e4 = __expf(v4 - m);
    const float inv = __fdividef(1.0f, e0 + e1 + e2 + e3 + e4);
    float* o = out + (size_t)(row0 + tid) * 5;
    o[0] = e0 * inv; o[1] = e1 * inv; o[2] = e2 * inv; o[3] = e3 * inv; o[4] = e4 * inv;
  }
}

extern "C" void kernel_launch(void* const* d_in, const int* in_sizes, int n_in,
                              void* d_out, int out_size, void* d_ws, size_t ws_size,
                              hipStream_t stream) {
  (void)in_sizes; (void)n_in; (void)d_ws; (void)ws_size; (void)out_size;
  lstm_r20_kernel<<<dim3(kBlocks), dim3(kThr), 0, stream>>>(
      (const float*)d_in[0],
      (const float*)d_in[1], (const float*)d_in[2],
      (const float*)d_in[3], (const float*)d_in[4],
      (const float*)d_in[5], (const float*)d_in[6],
      (const float*)d_in[7], (const float*)d_in[8],
      (const float*)d_in[9], (const float*)d_in[10],
      (float*)d_out);
}